// Round 20
// baseline (157.894 us; speedup 1.0000x reference)
//
#include <hip/hip_runtime.h>

typedef unsigned int uint;
typedef unsigned short ushort;
typedef __attribute__((ext_vector_type(8))) short short8;   // 8 bf16
typedef __attribute__((ext_vector_type(4))) float f32x4;

#define NSH   100
#define NPRIM 8
#define NAOC  280
#define NAOS  260
#define NATOM 20
#define KP    320           // 20 atoms x 16 k (14 real + 2 zero)
#define NKB   10
#define NPTS  512           // points per block
#define NTILE 16            // 32-pt tiles per block
#define NTHR  512           // 8 waves: 0-3 consumers, 4-7 producers
#define NCOLP 272
#define BCH   (32 * NCOLP)  // ushorts per chunk image (8704)
#define RSQRT3 0.57735026918962576f
#define LOG2E  1.4426950408889634f

// LDS: single A image [40 cells][32 p][16B] hi+lo, rebuilt per tile by producers.
#define O_AH    0        // 20480
#define O_AL    20480    // -> 40960
#define O_ZETA  40960    // 3200
#define O_COEF  44160    // 3200
#define O_CEN   47360    // 320
#define O_CX    47680    // 2048 (512 f32)
#define O_CY    49728    // 2048
#define O_CZ    51776    // 2048 -> 53824
#define POOLSZ  53824    // < 64KB static; 1 block/CU

__device__ __forceinline__ ushort bf16_rne(float x) {
    uint u = __float_as_uint(x);
    return (ushort)((u + 0x7FFFu + ((u >> 16) & 1u)) >> 16);
}
__device__ __forceinline__ float bf16_to_f(ushort h) {
    return __uint_as_float(((uint)h) << 16);
}
__device__ __forceinline__ uint cvt_pk_bf16(float a, float b) {
    uint r;
    asm("v_cvt_pk_bf16_f32 %0, %1, %2" : "=v"(r) : "v"(a), "v"(b));
    return r;
}

// B source in atom-major 16-padded k ordering (norm + d-anorm folded in)
__device__ __forceinline__ float b_src(const float* __restrict__ c2s,
                                       const float* __restrict__ norm,
                                       int kp, int col) {
    if (kp >= KP || col >= NAOS) return 0.0f;
    int a = kp >> 4, i = kp & 15;
    if (i >= 14) return 0.0f;
    int ksrc; float an = 1.0f;
    if (i < 2)      ksrc = 2 * a + i;
    else if (i < 8) ksrc = 40 + 6 * a + (i - 2);
    else {
        ksrc = 160 + 6 * a + (i - 8);
        if (i == 8 || i == 11 || i == 13) an = RSQRT3;
    }
    return c2s[ksrc * NAOS + col] * norm[ksrc] * an;
}

__global__ void prep_b(const float* __restrict__ c2s, const float* __restrict__ norm,
                       ushort* __restrict__ wsHi, ushort* __restrict__ wsLo) {
    int id = blockIdx.x * 256 + threadIdx.x;
    if (id >= KP * NCOLP) return;
    int k = id / NCOLP, col = id % NCOLP;
    float v = b_src(c2s, norm, k, col);
    ushort hi = bf16_rne(v);
    ushort lo = bf16_rne(v - bf16_to_f(hi));
    int off = (k >> 5) * BCH +
              (((col >> 4) * 4 + ((k & 31) >> 3)) * 16 + (col & 15)) * 8 + (k & 7);
    wsHi[off] = hi;
    wsLo[off] = lo;
}

template <bool USEWS>
__global__ __launch_bounds__(NTHR, 1) void gto_mfma(
    const float* __restrict__ coords, const float* __restrict__ centers,
    const float* __restrict__ zetas, const float* __restrict__ coeffs,
    const float* __restrict__ norm, const float* __restrict__ c2s,
    const ushort* __restrict__ wsHi, const ushort* __restrict__ wsLo,
    float* __restrict__ out, int n)
{
    __shared__ __align__(16) char smem[POOLSZ];
    float*  sZeta = (float*)(smem + O_ZETA);
    float*  sCoef = (float*)(smem + O_COEF);
    float4* sCen4 = (float4*)(smem + O_CEN);
    float*  sCx   = (float*)(smem + O_CX);
    float*  sCy   = (float*)(smem + O_CY);
    float*  sCz   = (float*)(smem + O_CZ);

    const int t = threadIdx.x;
    const int P0 = blockIdx.x * NPTS;

    // ---- stage constants ----
    for (int i = t; i < NSH * NPRIM; i += NTHR) {
        sZeta[i] = zetas[i] * LOG2E;
        sCoef[i] = coeffs[i];
    }
    if (t < NATOM)
        sCen4[t] = make_float4(centers[3 * t], centers[3 * t + 1], centers[3 * t + 2], 0.0f);
    for (int i = t; i < NPTS * 3; i += NTHR) {
        int gi = P0 * 3 + i;
        float v = (gi < 3 * n) ? coords[gi] : 0.0f;
        int p = i / 3, c = i - 3 * (i / 3);
        if (c == 0) sCx[p] = v; else if (c == 1) sCy[p] = v; else sCz[p] = v;
    }

    const bool isProd = (t >= 256);
    // consumer ids
    const int w = t >> 6, lane = t & 63, lr = lane & 15, lg4 = lane >> 4;
    const int wc = (w < 4) ? w : 0;   // safe pointer math for producer threads too
    // producer ids
    const int u = t & 255, s = u >> 5, pAp = u & 31;
    const int nAtoms = (s < 4) ? 3 : 2;
    const int aBase  = (s < 4) ? 3 * s : 12 + 2 * (s - 4);

    // ---- producer helpers ----
    auto atomEval = [&](int a, float cxp, float cyp, float czp,
                        uint (&h)[7], uint (&l)[7]) {
        float4 ca = sCen4[a];
        float dx = cxp - ca.x, dy = cyp - ca.y, dz = czp - ca.z;
        float r2 = dx * dx + dy * dy + dz * dz;
        float rad[5];
        #pragma unroll
        for (int sh = 0; sh < 5; ++sh) {
            const float* z = &sZeta[(5 * a + sh) * NPRIM];
            const float* cf = &sCoef[(5 * a + sh) * NPRIM];
            float4 z0 = *(const float4*)z,  z1 = *(const float4*)(z + 4);
            float4 c0 = *(const float4*)cf, c1 = *(const float4*)(cf + 4);
            float r = c0.x * __builtin_amdgcn_exp2f(-z0.x * r2);
            r += c0.y * __builtin_amdgcn_exp2f(-z0.y * r2);
            r += c0.z * __builtin_amdgcn_exp2f(-z0.z * r2);
            r += c0.w * __builtin_amdgcn_exp2f(-z0.w * r2);
            r += c1.x * __builtin_amdgcn_exp2f(-z1.x * r2);
            r += c1.y * __builtin_amdgcn_exp2f(-z1.y * r2);
            r += c1.z * __builtin_amdgcn_exp2f(-z1.z * r2);
            r += c1.w * __builtin_amdgcn_exp2f(-z1.w * r2);
            rad[sh] = r;
        }
        float xx = dx * dx, xy = dx * dy, xz = dx * dz;
        float yy = dy * dy, yz = dy * dz, zz = dz * dz;
        float v[14] = { rad[0], rad[1],
                        dx * rad[2], dy * rad[2], dz * rad[2],
                        dx * rad[3], dy * rad[3], dz * rad[3],
                        xx * rad[4], xy * rad[4], xz * rad[4],
                        yy * rad[4], yz * rad[4], zz * rad[4] };
        #pragma unroll
        for (int pr = 0; pr < 7; ++pr) {
            h[pr] = cvt_pk_bf16(v[2 * pr], v[2 * pr + 1]);
            float r0 = v[2 * pr]     - __uint_as_float(h[pr] << 16);
            float r1 = v[2 * pr + 1] - __uint_as_float(h[pr] & 0xffff0000u);
            l[pr] = cvt_pk_bf16(r0, r1);
        }
    };
    auto dumpCell = [&](int a, uint (&h)[7], uint (&l)[7]) {
        const int off = a * 1024 + pAp * 16;
        *(uint4*)(smem + O_AH + off)       = make_uint4(h[0], h[1], h[2], h[3]);
        *(uint4*)(smem + O_AH + off + 512) = make_uint4(h[4], h[5], h[6], 0u);
        *(uint4*)(smem + O_AL + off)       = make_uint4(l[0], l[1], l[2], l[3]);
        *(uint4*)(smem + O_AL + off + 512) = make_uint4(l[4], l[5], l[6], 0u);
    };

    uint h0[7] = {0}, l0[7] = {0}, h1[7] = {0}, l1[7] = {0}, h2[7] = {0}, l2[7] = {0};
    auto evalTile = [&](int tile) {
        const int pb = tile * 32 + pAp;
        const float cx = sCx[pb], cy = sCy[pb], cz = sCz[pb];
        atomEval(aBase, cx, cy, cz, h0, l0);
        atomEval(aBase + 1, cx, cy, cz, h1, l1);
        if (nAtoms == 3) atomEval(aBase + 2, cx, cy, cz, h2, l2);
    };
    auto dumpTile = [&]() {
        dumpCell(aBase, h0, l0);
        dumpCell(aBase + 1, h1, l1);
        if (nAtoms == 3) dumpCell(aBase + 2, h2, l2);
    };

    // consumer B bases (in-bounds for ALL threads via wc)
    const ushort* pHb  = wsHi + (4 * wc * 64 + lane) * 8;
    const ushort* pLb  = wsLo + (4 * wc * 64 + lane) * 8;
    const ushort* pH2b = wsHi + (16 * 64 + lane) * 8;
    const ushort* pL2b = wsLo + (16 * 64 + lane) * 8;

    __syncthreads();   // consts + coords staged
    if (isProd) { evalTile(0); dumpTile(); }
    __syncthreads();   // img(0) ready

    #pragma unroll 1
    for (int tl = 0; tl < NTILE; ++tl) {
        if (!isProd) {
            // ---- consumer: k-loop over img (tile tl) ----
            f32x4 acc[5][2];
            #pragma unroll
            for (int i = 0; i < 5; ++i)
                #pragma unroll
                for (int mt = 0; mt < 2; ++mt)
                    acc[i][mt] = (f32x4){0.0f, 0.0f, 0.0f, 0.0f};

            #pragma unroll 1
            for (int kb = 0; kb < NKB; ++kb) {
                short8 bh[5], bl[5];
                if (USEWS) {
                    const size_t o = (size_t)kb * BCH;
                    #pragma unroll
                    for (int i = 0; i < 4; ++i) {
                        bh[i] = *(const short8*)(pHb + o + i * 512);
                        bl[i] = *(const short8*)(pLb + o + i * 512);
                    }
                    if (w == 0) {
                        bh[4] = *(const short8*)(pH2b + o);
                        bl[4] = *(const short8*)(pL2b + o);
                    }
                } else {
                    #pragma unroll
                    for (int i = 0; i < 5; ++i) {
                        int nt = (i == 4) ? 16 : (4 * w + i);
                        #pragma unroll
                        for (int j = 0; j < 8; ++j) {
                            int k = kb * 32 + lg4 * 8 + j;
                            float v = b_src(c2s, norm, k, nt * 16 + lr);
                            ushort hi = bf16_rne(v);
                            bh[i][j] = (short)hi;
                            bl[i][j] = (short)bf16_rne(v - bf16_to_f(hi));
                        }
                    }
                }
                short8 aH[2], aL[2];
                #pragma unroll
                for (int mt = 0; mt < 2; ++mt) {
                    const int off = (kb * 4 + lg4) * 512 + (mt * 16 + lr) * 16;
                    aH[mt] = *(const short8*)(smem + O_AH + off);
                    aL[mt] = *(const short8*)(smem + O_AL + off);
                }
                #pragma unroll
                for (int i = 0; i < 5; ++i) {
                    if (i < 4 || w == 0) {
                        #pragma unroll
                        for (int mt = 0; mt < 2; ++mt)
                            acc[i][mt] = __builtin_amdgcn_mfma_f32_16x16x32_bf16(aH[mt], bh[i], acc[i][mt], 0, 0, 0);
                        #pragma unroll
                        for (int mt = 0; mt < 2; ++mt)
                            acc[i][mt] = __builtin_amdgcn_mfma_f32_16x16x32_bf16(aH[mt], bl[i], acc[i][mt], 0, 0, 0);
                        #pragma unroll
                        for (int mt = 0; mt < 2; ++mt)
                            acc[i][mt] = __builtin_amdgcn_mfma_f32_16x16x32_bf16(aL[mt], bh[i], acc[i][mt], 0, 0, 0);
                    }
                }
            }
            // ---- consumer: direct epilogue.
            //      R18/R19 CRASH FIX: tile 16 (nt=16) spans cols 256..271 but
            //      NAOS=260 — guard col < NAOS (lr<4 for the tail tile). ----
            #pragma unroll
            for (int i = 0; i < 5; ++i) {
                if (i < 4 || w == 0) {
                    int nt = (i == 4) ? 16 : (4 * w + i);
                    int col = nt * 16 + lr;
                    if (col < NAOS) {
                        #pragma unroll
                        for (int mt = 0; mt < 2; ++mt) {
                            #pragma unroll
                            for (int r = 0; r < 4; ++r) {
                                int P = P0 + tl * 32 + mt * 16 + lg4 * 4 + r;
                                if (P < n) out[(size_t)P * NAOS + col] = acc[i][mt][r];
                            }
                        }
                    }
                }
            }
        } else if (tl + 1 < NTILE) {
            evalTile(tl + 1);   // producer: next tile into registers
        }
        __syncthreads();   // consumers done reading img(tl)
        if (isProd && tl + 1 < NTILE) dumpTile();
        __syncthreads();   // img(tl+1) ready
    }
}

extern "C" void kernel_launch(void* const* d_in, const int* in_sizes, int n_in,
                              void* d_out, int out_size, void* d_ws, size_t ws_size,
                              hipStream_t stream) {
    const float* coords  = (const float*)d_in[0];
    const float* centers = (const float*)d_in[1];
    const float* zetas   = (const float*)d_in[2];
    const float* coeffs  = (const float*)d_in[3];
    const float* norm    = (const float*)d_in[4];
    const float* c2s     = (const float*)d_in[5];
    float* out = (float*)d_out;
    int n = in_sizes[0] / 3;
    int grid = (n + NPTS - 1) / NPTS;

    ushort* wsHi = (ushort*)d_ws;
    ushort* wsLo = wsHi + (size_t)KP * NCOLP;
    const size_t WS_NEED = (size_t)2 * KP * NCOLP * sizeof(ushort);

    if (ws_size >= WS_NEED) {
        prep_b<<<(KP * NCOLP + 255) / 256, 256, 0, stream>>>(c2s, norm, wsHi, wsLo);
        gto_mfma<true><<<grid, NTHR, 0, stream>>>(coords, centers, zetas, coeffs, norm, c2s,
                                                  wsHi, wsLo, out, n);
    } else {
        gto_mfma<false><<<grid, NTHR, 0, stream>>>(coords, centers, zetas, coeffs, norm, c2s,
                                                   nullptr, nullptr, out, n);
    }
}

// Round 21
// 90.049 us; speedup vs baseline: 1.7534x; 1.7534x over previous
//
#include <hip/hip_runtime.h>

typedef unsigned int uint;
typedef unsigned short ushort;
typedef __attribute__((ext_vector_type(8))) short short8;   // 8 bf16
typedef __attribute__((ext_vector_type(4))) float f32x4;

#define NSH   100
#define NPRIM 8
#define NAOC  280
#define NAOS  260
#define NATOM 20
#define KP    320           // 20 atoms x 16 k (14 real + 2 zero)
#define NKB   10
#define MT    32            // points per block
#define NTHR  256
#define NCOLP 272
#define BCH   (32 * NCOLP)  // ushorts per chunk image (8704)
#define RSQRT3 0.57735026918962576f
#define LOG2E  1.4426950408889634f
#define EPS   276           // epilogue row stride (floats)

// LDS layout. A image [40 cells][32 p][16B] built ONCE, conflict-free b128.
// Epilogue bounce [0..35328) aliases the (then-dead) A images.
#define O_AH    0        // 40*512 = 20480
#define O_AL    20480    // 20480 -> 40960
#define O_ZETA  40960    // 3200
#define O_COEF  44160    // 3200
#define O_CEN   47360    // 320
#define O_CX    47680    // 128
#define O_CY    47808    // 128
#define O_CZ    47936    // 128 -> 48064
#define POOLSZ  48064    // 3 blocks/CU (LDS); VGPR budget 512/3 ~ 168

__device__ __forceinline__ ushort bf16_rne(float x) {
    uint u = __float_as_uint(x);
    return (ushort)((u + 0x7FFFu + ((u >> 16) & 1u)) >> 16);
}
__device__ __forceinline__ float bf16_to_f(ushort h) {
    return __uint_as_float(((uint)h) << 16);
}
__device__ __forceinline__ uint cvt_pk_bf16(float a, float b) {
    uint r;
    asm("v_cvt_pk_bf16_f32 %0, %1, %2" : "=v"(r) : "v"(a), "v"(b));
    return r;
}

// B source in atom-major 16-padded k ordering: k' = 16a + i,
// i: 0,1 = s; 2..4 = p0 xyz; 5..7 = p1 xyz; 8..13 = d (xx,xy,xz,yy,yz,zz); 14,15 = 0.
// normalization and the d anorm (1/sqrt(3) on xx,yy,zz) folded in.
__device__ __forceinline__ float b_src(const float* __restrict__ c2s,
                                       const float* __restrict__ norm,
                                       int kp, int col) {
    if (kp >= KP || col >= NAOS) return 0.0f;
    int a = kp >> 4, i = kp & 15;
    if (i >= 14) return 0.0f;
    int ksrc; float an = 1.0f;
    if (i < 2)      ksrc = 2 * a + i;
    else if (i < 8) ksrc = 40 + 6 * a + (i - 2);
    else {
        ksrc = 160 + 6 * a + (i - 8);
        if (i == 8 || i == 11 || i == 13) an = RSQRT3;
    }
    return c2s[ksrc * NAOS + col] * norm[ksrc] * an;
}

// ---- prep: permuted+scaled cart2sph -> bf16 hi/lo MFMA frag image ----
__global__ void prep_b(const float* __restrict__ c2s, const float* __restrict__ norm,
                       ushort* __restrict__ wsHi, ushort* __restrict__ wsLo) {
    int id = blockIdx.x * 256 + threadIdx.x;
    if (id >= KP * NCOLP) return;
    int k = id / NCOLP, col = id % NCOLP;
    float v = b_src(c2s, norm, k, col);
    ushort hi = bf16_rne(v);
    ushort lo = bf16_rne(v - bf16_to_f(hi));
    int off = (k >> 5) * BCH +
              (((col >> 4) * 4 + ((k & 31) >> 3)) * 16 + (col & 15)) * 8 + (k & 7);
    wsHi[off] = hi;
    wsLo[off] = lo;
}

template <bool USEWS>
__global__ __launch_bounds__(NTHR, 3) void gto_mfma(
    const float* __restrict__ coords, const float* __restrict__ centers,
    const float* __restrict__ zetas, const float* __restrict__ coeffs,
    const float* __restrict__ norm, const float* __restrict__ c2s,
    const ushort* __restrict__ wsHi, const ushort* __restrict__ wsLo,
    float* __restrict__ out, int n)
{
    __shared__ __align__(16) char smem[POOLSZ];
    float*  sZeta = (float*)(smem + O_ZETA);
    float*  sCoef = (float*)(smem + O_COEF);
    float4* sCen4 = (float4*)(smem + O_CEN);
    float*  sCx   = (float*)(smem + O_CX);
    float*  sCy   = (float*)(smem + O_CY);
    float*  sCz   = (float*)(smem + O_CZ);

    const int t = threadIdx.x, lane = t & 63, w = t >> 6;
    const int lr = lane & 15, lg4 = lane >> 4;
    const int P0 = blockIdx.x * MT;

    // ---- stage constants ----
    for (int i = t; i < NSH * NPRIM; i += NTHR) {
        sZeta[i] = zetas[i] * LOG2E;           // pre-fold log2e for v_exp_f32
        sCoef[i] = coeffs[i];
    }
    if (t < NATOM)
        sCen4[t] = make_float4(centers[3 * t], centers[3 * t + 1], centers[3 * t + 2], 0.0f);
    if (t < MT * 3) {
        int gi = P0 * 3 + t;
        float v = (gi < 3 * n) ? coords[gi] : 0.0f;
        int p = t / 3, c = t - 3 * (t / 3);
        if (c == 0) sCx[p] = v; else if (c == 1) sCy[p] = v; else sCz[p] = v;
    }
    __syncthreads();

    // ---- A-build: FULLY STATIC per (point, atom); 16-k cells, b128 writes ----
    const int pA = t & 31, ag = t >> 5;
    const float cxp = sCx[pA], cyp = sCy[pA], czp = sCz[pA];

    auto doAtom = [&](int a) {
        float4 ca = sCen4[a];
        float dx = cxp - ca.x, dy = cyp - ca.y, dz = czp - ca.z;
        float r2 = dx * dx + dy * dy + dz * dz;
        float rad[5];
        #pragma unroll
        for (int sh = 0; sh < 5; ++sh) {
            const float* z = &sZeta[(5 * a + sh) * NPRIM];
            const float* cf = &sCoef[(5 * a + sh) * NPRIM];
            float4 z0 = *(const float4*)z,  z1 = *(const float4*)(z + 4);
            float4 c0 = *(const float4*)cf, c1 = *(const float4*)(cf + 4);
            float r = c0.x * __builtin_amdgcn_exp2f(-z0.x * r2);
            r += c0.y * __builtin_amdgcn_exp2f(-z0.y * r2);
            r += c0.z * __builtin_amdgcn_exp2f(-z0.z * r2);
            r += c0.w * __builtin_amdgcn_exp2f(-z0.w * r2);
            r += c1.x * __builtin_amdgcn_exp2f(-z1.x * r2);
            r += c1.y * __builtin_amdgcn_exp2f(-z1.y * r2);
            r += c1.z * __builtin_amdgcn_exp2f(-z1.z * r2);
            r += c1.w * __builtin_amdgcn_exp2f(-z1.w * r2);
            rad[sh] = r;
        }
        float xx = dx * dx, xy = dx * dy, xz = dx * dz;
        float yy = dy * dy, yz = dy * dz, zz = dz * dz;
        float v[14] = { rad[0], rad[1],
                        dx * rad[2], dy * rad[2], dz * rad[2],
                        dx * rad[3], dy * rad[3], dz * rad[3],
                        xx * rad[4], xy * rad[4], xz * rad[4],
                        yy * rad[4], yz * rad[4], zz * rad[4] };
        uint h[7], l[7];
        #pragma unroll
        for (int pr = 0; pr < 7; ++pr) {
            h[pr] = cvt_pk_bf16(v[2 * pr], v[2 * pr + 1]);
            float r0 = v[2 * pr]     - __uint_as_float(h[pr] << 16);
            float r1 = v[2 * pr + 1] - __uint_as_float(h[pr] & 0xffff0000u);
            l[pr] = cvt_pk_bf16(r0, r1);
        }
        const int off = a * 1024 + pA * 16;   // cells 2a, 2a+1; 16B aligned
        *(uint4*)(smem + O_AH + off)       = make_uint4(h[0], h[1], h[2], h[3]);
        *(uint4*)(smem + O_AH + off + 512) = make_uint4(h[4], h[5], h[6], 0u);
        *(uint4*)(smem + O_AL + off)       = make_uint4(l[0], l[1], l[2], l[3]);
        *(uint4*)(smem + O_AL + off + 512) = make_uint4(l[4], l[5], l[6], 0u);
    };
    if (ag < 4) { doAtom(3 * ag); doAtom(3 * ag + 1); doAtom(3 * ag + 2); }
    else        { int b = 12 + 2 * (ag - 4); doAtom(b); doAtom(b + 1); }
    __syncthreads();   // A image complete — barrier-free k-loop follows

    // ---- B running pointers: wave w owns tiles {4w..4w+3} (+16 for w0) ----
    const ushort* pH  = wsHi + (4 * w * 64 + lane) * 8;
    const ushort* pL  = wsLo + (4 * w * 64 + lane) * 8;
    const ushort* pH2 = wsHi + (16 * 64 + lane) * 8;
    const ushort* pL2 = wsLo + (16 * 64 + lane) * 8;

    f32x4 acc[5][2];
    #pragma unroll
    for (int i = 0; i < 5; ++i)
        #pragma unroll
        for (int mt = 0; mt < 2; ++mt)
            acc[i][mt] = (f32x4){0.0f, 0.0f, 0.0f, 0.0f};

    // ---- barrier-free MFMA k-loop; B tiles batch-loaded per chunk ----
    #pragma unroll 1
    for (int kb = 0; kb < NKB; ++kb) {
        // batched B loads (MLP: all issued back-to-back, one L2 latency/chunk)
        short8 bh[5], bl[5];
        if (USEWS) {
            #pragma unroll
            for (int i = 0; i < 4; ++i) {
                bh[i] = *(const short8*)(pH + i * 512);
                bl[i] = *(const short8*)(pL + i * 512);
            }
            if (w == 0) {
                bh[4] = *(const short8*)pH2;
                bl[4] = *(const short8*)pL2;
            }
        } else {
            #pragma unroll
            for (int i = 0; i < 5; ++i) {
                int nt = (i == 4) ? 16 : (4 * w + i);
                #pragma unroll
                for (int j = 0; j < 8; ++j) {
                    int k = kb * 32 + lg4 * 8 + j;
                    int col = nt * 16 + lr;
                    float v = b_src(c2s, norm, k, col);
                    ushort hi = bf16_rne(v);
                    bh[i][j] = (short)hi;
                    bl[i][j] = (short)bf16_rne(v - bf16_to_f(hi));
                }
            }
        }

        short8 aH[2], aL[2];
        #pragma unroll
        for (int mt = 0; mt < 2; ++mt) {
            const int off = (kb * 4 + lg4) * 512 + (mt * 16 + lr) * 16;
            aH[mt] = *(const short8*)(smem + O_AH + off);
            aL[mt] = *(const short8*)(smem + O_AL + off);
        }

        #pragma unroll
        for (int i = 0; i < 5; ++i) {
            if (i < 4 || w == 0) {
                #pragma unroll
                for (int mt = 0; mt < 2; ++mt)
                    acc[i][mt] = __builtin_amdgcn_mfma_f32_16x16x32_bf16(aH[mt], bh[i], acc[i][mt], 0, 0, 0);
                #pragma unroll
                for (int mt = 0; mt < 2; ++mt)
                    acc[i][mt] = __builtin_amdgcn_mfma_f32_16x16x32_bf16(aH[mt], bl[i], acc[i][mt], 0, 0, 0);
                #pragma unroll
                for (int mt = 0; mt < 2; ++mt)
                    acc[i][mt] = __builtin_amdgcn_mfma_f32_16x16x32_bf16(aL[mt], bh[i], acc[i][mt], 0, 0, 0);
            }
        }
        pH += BCH; pL += BCH; pH2 += BCH; pL2 += BCH;
    }

    // ---- epilogue: single 32-row bounce (aliases dead A images) ----
    __syncthreads();   // all waves done reading A image
    float* ep = (float*)smem;
    #pragma unroll
    for (int i = 0; i < 5; ++i) {
        if (i < 4 || w == 0) {
            int nt = (i == 4) ? 16 : (4 * w + i);
            int col = nt * 16 + lr;
            #pragma unroll
            for (int mt = 0; mt < 2; ++mt)
                #pragma unroll
                for (int r = 0; r < 4; ++r)
                    ep[(mt * 16 + lg4 * 4 + r) * EPS + col] = acc[i][mt][r];
        }
    }
    __syncthreads();

    #pragma unroll
    for (int j = 0; j < 8; ++j) {
        int row = w + j * 4;
        int P = P0 + row;
        if (P < n)
            *(float4*)&out[(size_t)P * NAOS + lane * 4] = *(const float4*)&ep[row * EPS + lane * 4];
    }
    if (w == 1 && lane < MT) {
        int P = P0 + lane;
        if (P < n)
            *(float4*)&out[(size_t)P * NAOS + 256] = *(const float4*)&ep[lane * EPS + 256];
    }
}

extern "C" void kernel_launch(void* const* d_in, const int* in_sizes, int n_in,
                              void* d_out, int out_size, void* d_ws, size_t ws_size,
                              hipStream_t stream) {
    const float* coords  = (const float*)d_in[0];
    const float* centers = (const float*)d_in[1];
    const float* zetas   = (const float*)d_in[2];
    const float* coeffs  = (const float*)d_in[3];
    const float* norm    = (const float*)d_in[4];
    const float* c2s     = (const float*)d_in[5];
    float* out = (float*)d_out;
    int n = in_sizes[0] / 3;
    int grid = (n + MT - 1) / MT;

    ushort* wsHi = (ushort*)d_ws;
    ushort* wsLo = wsHi + (size_t)KP * NCOLP;
    const size_t WS_NEED = (size_t)2 * KP * NCOLP * sizeof(ushort);   // 348160

    if (ws_size >= WS_NEED) {
        prep_b<<<(KP * NCOLP + 255) / 256, 256, 0, stream>>>(c2s, norm, wsHi, wsLo);
        gto_mfma<true><<<grid, NTHR, 0, stream>>>(coords, centers, zetas, coeffs, norm, c2s,
                                                  wsHi, wsLo, out, n);
    } else {
        gto_mfma<false><<<grid, NTHR, 0, stream>>>(coords, centers, zetas, coeffs, norm, c2s,
                                                   nullptr, nullptr, out, n);
    }
}